// Round 6
// baseline (576.921 us; speedup 1.0000x reference)
//
#include <hip/hip_runtime.h>

typedef __bf16 bf16x8 __attribute__((ext_vector_type(8)));
typedef float  f32x4  __attribute__((ext_vector_type(4)));
typedef unsigned int u32x4 __attribute__((ext_vector_type(4)));

#define MFMA(a, b, c) __builtin_amdgcn_mfma_f32_16x16x32_bf16((a), (b), (c), 0, 0, 0)

#define THREADS 512
#define WAVES   8
#define CPW     4     // crystals per wave
#define CPB     32    // crystals per block (8 waves x 4)
#define MT      32    // nodes per tile (2 x 16-row halves)

// workspace layout: [seg table][bf16 weight pack][bf16 cry][bf16 fea]
#define SEG_INTS  16416
#define SEG_BYTES (SEG_INTS * 4)       // 65664
#define O_WM1 0
#define O_WM2 65536
#define O_WA1 131072
#define O_WA2 262144
#define W_ELEMS 262656
#define W_BYTES (W_ELEMS * 2)          // 525312

// LDS weight region byte offsets (within wlds): two 128-row x 256 B panels
#define LM1B 0        // Wm1
#define LM2B 32768    // Wm2   (end 65536)

__device__ __forceinline__ bf16x8 cvt8(const float* pf) {
    float4 a = *(const float4*)pf, b = *(const float4*)(pf + 4);
    bf16x8 o;
    o[0] = (__bf16)a.x; o[1] = (__bf16)a.y; o[2] = (__bf16)a.z; o[3] = (__bf16)a.w;
    o[4] = (__bf16)b.x; o[5] = (__bf16)b.y; o[6] = (__bf16)b.z; o[7] = (__bf16)b.w;
    return o;
}

__device__ __forceinline__ unsigned pk2(float a, float b) {
    unsigned short ua = __builtin_bit_cast(unsigned short, (__bf16)a);
    unsigned short ub = __builtin_bit_cast(unsigned short, (__bf16)b);
    return (unsigned)ua | ((unsigned)ub << 16);
}

__device__ __forceinline__ int lower_bound(const int* __restrict__ a, int n, int v) {
    int lo = 0, hi = n;
    while (lo < hi) { int mid = (lo + hi) >> 1; if (a[mid] < v) lo = mid + 1; else hi = mid; }
    return lo;
}

template<bool WB>
__device__ __forceinline__ bf16x8 wfrag(const __bf16* wb, const float* wf, size_t idx) {
    if constexpr (WB) return *(const bf16x8*)(wb + idx);
    else              return cvt8(wf + idx);
}

// ---------------------------------------------------------------------------
// Merged prep: block ranges do [seg table][weight pack][cry cast][fea cast].
// bf16 casts are bitwise-identical to the in-kernel cvt8 rounding.
// ---------------------------------------------------------------------------
__global__ __launch_bounds__(256) void prep3_kernel(
    const float* __restrict__ Wm1, const float* __restrict__ Wm2,
    const float* __restrict__ Wa1, const float* __restrict__ Wa2,
    const float* __restrict__ fea, const float* __restrict__ cry,
    const int* __restrict__ index, int N, int S,
    int segBlocks, int packBlocks, int cryBlocks,
    int* __restrict__ seg, __bf16* __restrict__ wb,
    __bf16* __restrict__ cryb, __bf16* __restrict__ feab, int full)
{
    int b = blockIdx.x;
    if (b < segBlocks) {
        int c = b * 256 + threadIdx.x;
        if (c <= S) seg[c] = lower_bound(index, N, c);
        return;
    }
    if (!full) return;
    b -= segBlocks;
    if (b < packBlocks) {
        int i8 = b * 256 + threadIdx.x;
        if (i8 >= W_ELEMS / 8) return;
        int i = i8 * 8;
        const float* src; int s;
        if      (i < O_WM2) { src = Wm1; s = i; }
        else if (i < O_WA1) { src = Wm2; s = i - O_WM2; }
        else if (i < O_WA2) { src = Wa1; s = i - O_WA1; }
        else                { src = Wa2; s = i - O_WA2; }
        *(bf16x8*)(wb + i) = cvt8(src + s);
        return;
    }
    b -= packBlocks;
    if (b < cryBlocks) {
        int i = b * 256 + threadIdx.x;
        if (i < S * 16) *(bf16x8*)(cryb + (size_t)i * 8) = cvt8(cry + (size_t)i * 8);
        return;
    }
    b -= cryBlocks;
    int i = b * 256 + threadIdx.x;
    if (i < N * 16) *(bf16x8*)(feab + (size_t)i * 8) = cvt8(fea + (size_t)i * 8);
}

// ---------------------------------------------------------------------------
// Fused kernel: 512 threads (8 waves), 2 blocks/CU (4 waves/SIMD).
// LDS = Wm1+Wm2 panels (64 KiB, XOR-swizzled) + crylds (16 KiB) = exactly
// 80 KiB -> two blocks co-resident. Wa1 is read from the bf16 pack in
// global (L2-resident: 4 heads x 32 KiB node-half per XCD). bm1 read via
// cached global float4. launch_bounds(512,2): min-2-blocks/CU semantics ->
// VGPR cap 128, kernel needs ~100 (R3-measured) -> no scratch spills.
// Block = one head x 32 crystals; wave w owns [c0+4w, c0+4w+4); no
// main-loop barriers. XCD-aware mapping keeps a crystal-group's 4 heads on
// one XCD. Per 32-node tile: two 16-row halves, each fully processed
// (GEMM3->logits, GEMM1 swapped + repack, GEMM2, softmax run-walk).
// MFMA 16x16x32 bf16: A/B[idx=lane&15][k=(lane>>4)*8+j]; D col=lane&15,
// row=(lane>>4)*4+reg.
// ---------------------------------------------------------------------------
template<bool WB, bool SEG, bool FB>
__global__ __launch_bounds__(THREADS, 2) void fused7_kernel(
    const float* __restrict__ fea, const float* __restrict__ cry,
    const float* __restrict__ Wm1, const float* __restrict__ bm1,
    const float* __restrict__ Wm2, const float* __restrict__ bm2,
    const float* __restrict__ Wa1, const float* __restrict__ ba1,
    const float* __restrict__ Wa2, const float* __restrict__ ba2,
    const __bf16* __restrict__ wb, const int* __restrict__ seg,
    const __bf16* __restrict__ feab, const __bf16* __restrict__ cryb,
    const int* __restrict__ index, int N, int S, float* __restrict__ out)
{
    __shared__ __align__(16) __bf16 wlds[32768];       // 64 KiB Wm1|Wm2
    __shared__ float crylds[WAVES][CPW][128];           // 16 KiB cry.Wa1cry^T

    // ---- XCD-aware block -> (head, crystal-group) mapping ----
    const int G = (S + CPB - 1) / CPB;
    int h, cg;
    if ((G & 7) == 0) {
        const int xcd = blockIdx.x & 7, j = blockIdx.x >> 3;
        h = j & 3; cg = xcd + 8 * (j >> 2);
    } else {
        h = blockIdx.x & 3; cg = blockIdx.x >> 2;
    }
    const int c0 = cg * CPB;
    const int t  = threadIdx.x;
    const int lane = t & 63, w = t >> 6, ml = lane & 15, q = lane >> 4;
    const int swzb = (ml & 7) << 4;
    const char* wbytes = (const char*)wlds;

    // ---- stage Wm1/Wm2 (swizzled source -> linear LDS); 2 panels x 32 KiB --
#pragma unroll
    for (int i = 0; i < 8; i++) {
        const int cb = (t + i * THREADS) << 4;   // [0, 65536)
        const int r = cb >> 15;
        const int local = cb & 32767;
        const int row = local >> 8;
        const int col8 = ((((local >> 4) & 15) ^ (row & 7)) << 3);
        bf16x8 v;
        if (r == 0) {
            if constexpr (WB) v = *(const bf16x8*)(wb + O_WM1 + (size_t)h * 16384 + row * 128 + col8);
            else              v = cvt8(Wm1 + (size_t)h * 16384 + (size_t)row * 128 + col8);
        } else {
            if constexpr (WB) v = *(const bf16x8*)(wb + O_WM2 + (size_t)h * 16384 + row * 128 + col8);
            else              v = cvt8(Wm2 + (size_t)h * 16384 + (size_t)row * 128 + col8);
        }
        *(bf16x8*)((char*)wlds + cb) = v;
    }
    __syncthreads();

    // ---- per-wave crystal range ----
    const int cw0 = min(c0 + w * CPW, S);
    const int cw1 = min(cw0 + CPW, S);
    int start, end;
    if constexpr (SEG) { start = seg[cw0]; end = seg[cw1]; }
    else { start = lower_bound(index, N, cw0); end = lower_bound(index, N, cw1); }

    // ---- hoisted per-lane biases (col = ot*16+ml of head h) ----
    float ba1v[8], bb2[8], wa2v[8];
#pragma unroll
    for (int ot = 0; ot < 8; ot++) {
        ba1v[ot] = ba1[h * 128 + ot * 16 + ml];
        bb2[ot]  = bm2[h * 128 + ot * 16 + ml];
        wa2v[ot] = Wa2[h * 128 + ot * 16 + ml];
    }
    const float ba2v = ba2[h];
    const float* bm1h = bm1 + h * 128;

    // ---- precompute cry contribution: D[crystal r][o] = cry_c . Wa1cry^T ----
    {
        bf16x8 cf[4];
#pragma unroll
        for (int kk = 0; kk < 4; kk++) {
            bf16x8 z;
#pragma unroll
            for (int j = 0; j < 8; j++) z[j] = (__bf16)0.f;
            if (ml < CPW && cw0 + ml < S) {
                if constexpr (FB) z = *(const bf16x8*)(cryb + (size_t)(cw0 + ml) * 128 + kk * 32 + q * 8);
                else              z = cvt8(cry + (size_t)(cw0 + ml) * 128 + kk * 32 + q * 8);
            }
            cf[kk] = z;
        }
#pragma unroll
        for (int ot = 0; ot < 8; ot++) {
            size_t wrow = (size_t)h * 32768 + (size_t)(ot * 16 + ml) * 256;
            f32x4 acc = {0.f, 0.f, 0.f, 0.f};
#pragma unroll
            for (int kk = 0; kk < 4; kk++)
                acc = MFMA(cf[kk], wfrag<WB>(wb + O_WA1, Wa1, wrow + 128 + kk * 32 + q * 8), acc);
            if (q == 0) {
#pragma unroll
                for (int r = 0; r < 4; r++) crylds[w][r][ot * 16 + ml] = acc[r];
            }
        }
    }

    float m_run = -1e30f, d_run = 0.f;
    float wacc[8] = {0.f,0.f,0.f,0.f,0.f,0.f,0.f,0.f};
    int cur_c = -1, emit_c = cw0;

    auto flushf = [&]() {
        float inv = 1.f / (d_run + 1e-16f);
        for (int z = emit_c; z < cur_c; z++)   // zero-fill empty crystals
            *(float2*)&out[(size_t)z * 512 + h * 128 + lane * 2] = make_float2(0.f, 0.f);
#pragma unroll
        for (int ot = 0; ot < 8; ot++) {
            float v = wacc[ot];
            v += __shfl_xor(v, 16);
            v += __shfl_xor(v, 32);
            if (q == 0) out[(size_t)cur_c * 512 + h * 128 + ot * 16 + ml] = v * inv;
            wacc[ot] = 0.f;
        }
        emit_c = cur_c + 1;
        m_run = -1e30f; d_run = 0.f;
    };

    for (int tb = start; tb < end; tb += MT) {
        int nv = end - tb; if (nv > MT) nv = MT;

        // ---- per-lane node index (rows 0..31 on lanes 0..31) ----
        const int iv = (lane < nv) ? index[tb + lane] : cw0;

        // ---- run-boundary mask for the whole tile ----
        unsigned long long bmask;
        {
            int ivp = __shfl(iv, lane > 0 ? lane - 1 : 0);
            bmask = __ballot(lane < nv && (lane == 0 || iv != ivp));
        }

        // ---- two 16-row halves, fully processed in sequence ----
        for (int s = 0; s < 2; s++) {
            const int lo = s * 16;
            if (lo >= nv) break;
            int hcnt = nv - lo; if (hcnt > 16) hcnt = 16;

            // -- fea fragments for this half (zero-pad invalid rows) --
            bf16x8 afh[4];
            {
                const int row = lo + ml;
                const bool val = row < nv;
#pragma unroll
                for (int kk = 0; kk < 4; kk++) {
                    bf16x8 z;
#pragma unroll
                    for (int j = 0; j < 8; j++) z[j] = (__bf16)0.f;
                    if (val) {
                        if constexpr (FB) z = *(const bf16x8*)(feab + (size_t)(tb + row) * 128 + kk * 32 + q * 8);
                        else              z = cvt8(fea + (size_t)(tb + row) * 128 + kk * 32 + q * 8);
                    }
                    afh[kk] = z;
                }
            }

            // -- GEMM3 (Wa1 node half from global/L2; cry half acc-init) --
            float lv4[4];
            {
                int cl4[4];
#pragma unroll
                for (int r = 0; r < 4; r++)
                    cl4[r] = __shfl(iv, lo + q * 4 + r) - cw0;
                float lsum[4] = {0.f, 0.f, 0.f, 0.f};
#pragma unroll
                for (int ot = 0; ot < 8; ot++) {
                    size_t wrow = (size_t)h * 32768 + (size_t)(ot * 16 + ml) * 256;
                    const int oc = ot * 16 + ml;
                    f32x4 acc;
#pragma unroll
                    for (int r = 0; r < 4; r++) acc[r] = crylds[w][cl4[r]][oc];
#pragma unroll
                    for (int kk = 0; kk < 4; kk++)
                        acc = MFMA(afh[kk], wfrag<WB>(wb + O_WA1, Wa1, wrow + kk * 32 + q * 8), acc);
#pragma unroll
                    for (int r = 0; r < 4; r++) {
                        float v = acc[r] + ba1v[ot]; v = v >= 0.f ? v : 0.01f * v;
                        lsum[r] += v * wa2v[ot];
                    }
                }
#pragma unroll
                for (int rr = 0; rr < 4; rr++) {
                    float x = lsum[rr];
                    x += __shfl_xor(x, 1); x += __shfl_xor(x, 2);
                    x += __shfl_xor(x, 4); x += __shfl_xor(x, 8);
                    lv4[rr] = x + ba2v;   // logit of row lo + q*4 + rr
                }
            }

            // -- GEMM1 swapped (A=Wm1 from LDS, B=fea half) + repack --
            bf16x8 a2h[4];
#pragma unroll
            for (int kk = 0; kk < 4; kk++) {
                unsigned pw[2][2];   // [otl][p]
#pragma unroll
                for (int otl = 0; otl < 2; otl++) {
                    const int ot = kk * 2 + otl;
                    bf16x8 A[4];
#pragma unroll
                    for (int k4 = 0; k4 < 4; k4++)
                        A[k4] = *(const bf16x8*)(wbytes + LM1B + (ot * 16 + ml) * 256 + ((((k4 * 4 + q) << 4)) ^ swzb));
                    const float4 bq = *(const float4*)&bm1h[ot * 16 + q * 4];
                    f32x4 acc = {0.f, 0.f, 0.f, 0.f};
#pragma unroll
                    for (int k4 = 0; k4 < 4; k4++) acc = MFMA(A[k4], afh[k4], acc);
                    float v0 = acc[0] + bq.x, v1 = acc[1] + bq.y;
                    float v2 = acc[2] + bq.z, v3 = acc[3] + bq.w;
                    v0 = v0 >= 0.f ? v0 : 0.01f * v0;  v1 = v1 >= 0.f ? v1 : 0.01f * v1;
                    v2 = v2 >= 0.f ? v2 : 0.01f * v2;  v3 = v3 >= 0.f ? v3 : 0.01f * v3;
                    pw[otl][0] = pk2(v0, v1);
                    pw[otl][1] = pk2(v2, v3);
                }
                const int srcLo = (((2 * q) & 3) << 4) + ml;
                const int srcHi = (((2 * q + 1) & 3) << 4) + ml;
                const bool hiSel = (q >> 1) & 1;
                unsigned l0a = (unsigned)__shfl((int)pw[0][0], srcLo);
                unsigned l0b = (unsigned)__shfl((int)pw[1][0], srcLo);
                unsigned l1a = (unsigned)__shfl((int)pw[0][1], srcLo);
                unsigned l1b = (unsigned)__shfl((int)pw[1][1], srcLo);
                unsigned h0a = (unsigned)__shfl((int)pw[0][0], srcHi);
                unsigned h0b = (unsigned)__shfl((int)pw[1][0], srcHi);
                unsigned h1a = (unsigned)__shfl((int)pw[0][1], srcHi);
                unsigned h1b = (unsigned)__shfl((int)pw[1][1], srcHi);
                u32x4 wv4u = { hiSel ? l0b : l0a, hiSel ? l1b : l1a,
                               hiSel ? h0b : h0a, hiSel ? h1b : h1a };
                a2h[kk] = __builtin_bit_cast(bf16x8, wv4u);
            }

            // -- GEMM2 (Wm2 from LDS; bias-initialized accumulators) --
            f32x4 acc2h[8];
#pragma unroll
            for (int ot = 0; ot < 8; ot++) {
                bf16x8 B[4];
#pragma unroll
                for (int kk = 0; kk < 4; kk++)
                    B[kk] = *(const bf16x8*)(wbytes + LM2B + (ot * 16 + ml) * 256 + ((((kk * 4 + q) << 4)) ^ swzb));
                f32x4 acc = {bb2[ot], bb2[ot], bb2[ot], bb2[ot]};
#pragma unroll
                for (int kk = 0; kk < 4; kk++) acc = MFMA(a2h[kk], B[kk], acc);
                acc2h[ot] = acc;
            }

            // -- run walk for this half's rows [lo, lo+hcnt) --
            unsigned hm = (unsigned)((bmask >> lo) & 0xffffull) | 1u;
            if (hcnt < 16) hm &= (1u << hcnt) - 1u;
            while (hm) {
                int a = (int)__builtin_ctz(hm);
                hm &= hm - 1u;
                int b = hm ? (int)__builtin_ctz(hm) : hcnt;
                int c = __shfl(iv, lo + a);
                if (c != cur_c) {
                    if (cur_c >= 0) flushf();
                    cur_c = c;
                }
                float tmax = -1e30f;
#pragma unroll
                for (int rr = 0; rr < 4; rr++) {
                    int row = q * 4 + rr;
                    if (row >= a && row < b) tmax = fmaxf(tmax, lv4[rr]);
                }
                tmax = fmaxf(tmax, __shfl_xor(tmax, 16));
                tmax = fmaxf(tmax, __shfl_xor(tmax, 32));
                float m_new = fmaxf(m_run, tmax);
                float scf = __expf(m_run - m_new);
                d_run *= scf;
#pragma unroll
                for (int ot = 0; ot < 8; ot++) wacc[ot] *= scf;
                m_run = m_new;

                float wv4[4]; float dp = 0.f;
#pragma unroll
                for (int rr = 0; rr < 4; rr++) {
                    int row = q * 4 + rr;
                    float ww = (row >= a && row < b) ? __expf(lv4[rr] - m_run) : 0.f;
                    wv4[rr] = ww; dp += ww;
                }
                dp += __shfl_xor(dp, 16);
                dp += __shfl_xor(dp, 32);
                d_run += dp;
#pragma unroll
                for (int ot = 0; ot < 8; ot++) {
                    f32x4 acc = acc2h[ot];
                    wacc[ot] += wv4[0] * acc[0] + wv4[1] * acc[1]
                              + wv4[2] * acc[2] + wv4[3] * acc[3];
                }
            }
        }
    }

    if (cur_c >= 0) flushf();
    for (int z = emit_c; z < cw1; z++)   // trailing empty crystals
        *(float2*)&out[(size_t)z * 512 + h * 128 + lane * 2] = make_float2(0.f, 0.f);
}

// ---------------------------------------------------------------------------
extern "C" void kernel_launch(void* const* d_in, const int* in_sizes, int n_in,
                              void* d_out, int out_size, void* d_ws, size_t ws_size,
                              hipStream_t stream)
{
    const float* fea = (const float*)d_in[0];
    const float* cry = (const float*)d_in[1];
    const float* Wm1 = (const float*)d_in[2];
    const float* bm1 = (const float*)d_in[3];
    const float* Wm2 = (const float*)d_in[4];
    const float* bm2 = (const float*)d_in[5];
    const float* Wa1 = (const float*)d_in[6];
    const float* ba1 = (const float*)d_in[7];
    const float* Wa2 = (const float*)d_in[8];
    const float* ba2 = (const float*)d_in[9];
    const int* index = (const int*)d_in[10];

    const int N = in_sizes[0] / 128;      // 200000
    const int S = out_size / 512;         // 16384
    const int G = (S + CPB - 1) / CPB;
    const int grid = 4 * G;

    const int segBlocks  = (S + 1 + 255) / 256;
    const int packBlocks = (W_ELEMS / 8 + 255) / 256;
    const int cryBlocks  = (S * 16 + 255) / 256;
    const int feaBlocks  = (N * 16 + 255) / 256;
    const bool segFits = (S + 1) <= SEG_INTS;

    const size_t wOff   = (size_t)SEG_BYTES;
    const size_t cryOff = wOff + (size_t)W_BYTES;
    const size_t feaOff = cryOff + (size_t)S * 256;
    const size_t needSeg  = (size_t)SEG_BYTES;
    const size_t needFull = feaOff + (size_t)N * 256;

    if (segFits && ws_size >= needFull) {
        int* seg = (int*)d_ws;
        __bf16* wbp  = (__bf16*)((char*)d_ws + wOff);
        __bf16* cryb = (__bf16*)((char*)d_ws + cryOff);
        __bf16* feab = (__bf16*)((char*)d_ws + feaOff);
        prep3_kernel<<<segBlocks + packBlocks + cryBlocks + feaBlocks, 256, 0, stream>>>(
            Wm1, Wm2, Wa1, Wa2, fea, cry, index, N, S,
            segBlocks, packBlocks, cryBlocks, seg, wbp, cryb, feab, 1);
        fused7_kernel<true, true, true><<<grid, THREADS, 0, stream>>>(
            fea, cry, Wm1, bm1, Wm2, bm2, Wa1, ba1, Wa2, ba2,
            wbp, seg, feab, cryb, index, N, S, (float*)d_out);
    } else if (segFits && ws_size >= needSeg) {
        int* seg = (int*)d_ws;
        prep3_kernel<<<segBlocks, 256, 0, stream>>>(
            Wm1, Wm2, Wa1, Wa2, fea, cry, index, N, S,
            segBlocks, packBlocks, cryBlocks, seg, nullptr, nullptr, nullptr, 0);
        fused7_kernel<false, true, false><<<grid, THREADS, 0, stream>>>(
            fea, cry, Wm1, bm1, Wm2, bm2, Wa1, ba1, Wa2, ba2,
            nullptr, seg, nullptr, nullptr, index, N, S, (float*)d_out);
    } else {
        fused7_kernel<false, false, false><<<grid, THREADS, 0, stream>>>(
            fea, cry, Wm1, bm1, Wm2, bm2, Wa1, ba1, Wa2, ba2,
            nullptr, nullptr, nullptr, nullptr, index, N, S, (float*)d_out);
    }
}

// Round 7
// 570.901 us; speedup vs baseline: 1.0105x; 1.0105x over previous
//
#include <hip/hip_runtime.h>

typedef __bf16 bf16x8 __attribute__((ext_vector_type(8)));
typedef float  f32x4  __attribute__((ext_vector_type(4)));
typedef unsigned int u32x4 __attribute__((ext_vector_type(4)));

#define MFMA(a, b, c) __builtin_amdgcn_mfma_f32_16x16x32_bf16((a), (b), (c), 0, 0, 0)

#define THREADS 1024
#define WAVES   16
#define CPW     4     // crystals per wave
#define CPB     64    // crystals per block (16 waves x 4)
#define MT      32    // nodes per tile (2 x 16-row halves)

// LDS weight region byte offsets (within wlds): three 128-row x 256 B panels
#define LA1B 0        // Wa1 node half (cols 0..127)
#define LM1B 32768    // Wm1
#define LM2B 65536    // Wm2   (end 98304)

__device__ __forceinline__ bf16x8 cvt8(const float* pf) {
    float4 a = *(const float4*)pf, b = *(const float4*)(pf + 4);
    bf16x8 o;
    o[0] = (__bf16)a.x; o[1] = (__bf16)a.y; o[2] = (__bf16)a.z; o[3] = (__bf16)a.w;
    o[4] = (__bf16)b.x; o[5] = (__bf16)b.y; o[6] = (__bf16)b.z; o[7] = (__bf16)b.w;
    return o;
}

__device__ __forceinline__ unsigned pk2(float a, float b) {
    unsigned short ua = __builtin_bit_cast(unsigned short, (__bf16)a);
    unsigned short ub = __builtin_bit_cast(unsigned short, (__bf16)b);
    return (unsigned)ua | ((unsigned)ub << 16);
}

__device__ __forceinline__ int lower_bound(const int* __restrict__ a, int n, int v) {
    int lo = 0, hi = n;
    while (lo < hi) { int mid = (lo + hi) >> 1; if (a[mid] < v) lo = mid + 1; else hi = mid; }
    return lo;
}

// ---------------------------------------------------------------------------
// Single-dispatch fused kernel. 1024 threads = 16 waves; 1 block/CU
// (LDS 128.5 KiB) -> 4 waves/SIMD via amdgpu_waves_per_eu(4) (VGPR cap 128;
// body needs ~108, no spills -- launch_bounds' 2nd arg is min-BLOCKS/CU on
// this toolchain: (1024,4) clamped the cap to 64 and spilled, R4/R5).
// Block = one head x 64 crystals; wave w owns [c0+4w, c0+4w+4); no main-loop
// barriers. XCD-aware mapping keeps a crystal-group's 4 heads on one XCD.
// All three weight panels (Wa1 node half, Wm1, Wm2) staged once into LDS
// (XOR-swizzled) from f32 global (cvt8 = bitwise-identical to precast).
// Segment bounds: 5 parallel per-wave binary searches (no seg table, no
// prep dispatch). Per 32-node tile: two 16-row halves, each fully processed
// (GEMM3->logits, GEMM1 swapped + in-reg repack, GEMM2, softmax run-walk).
// MFMA 16x16x32 bf16: A/B[idx=lane&15][k=(lane>>4)*8+j]; D col=lane&15,
// row=(lane>>4)*4+reg.
// ---------------------------------------------------------------------------
__global__ __attribute__((amdgpu_flat_work_group_size(THREADS, THREADS),
                          amdgpu_waves_per_eu(4)))
void fused8_kernel(
    const float* __restrict__ fea, const float* __restrict__ cry,
    const float* __restrict__ Wm1, const float* __restrict__ bm1,
    const float* __restrict__ Wm2, const float* __restrict__ bm2,
    const float* __restrict__ Wa1, const float* __restrict__ ba1,
    const float* __restrict__ Wa2, const float* __restrict__ ba2,
    const int* __restrict__ index, int N, int S, float* __restrict__ out)
{
    __shared__ __align__(16) __bf16 wlds[49152];       // 96 KiB weights
    __shared__ float crylds[WAVES][CPW][128];           // 32 KiB cry.Wa1cry^T
    __shared__ float bm1lds[128];                       // 512 B

    // ---- XCD-aware block -> (head, crystal-group) mapping ----
    const int G = (S + CPB - 1) / CPB;
    int h, cg;
    if ((G & 7) == 0) {
        const int xcd = blockIdx.x & 7, j = blockIdx.x >> 3;
        h = j & 3; cg = xcd + 8 * (j >> 2);
    } else {
        h = blockIdx.x & 3; cg = blockIdx.x >> 2;
    }
    const int c0 = cg * CPB;
    const int t  = threadIdx.x;
    const int lane = t & 63, w = t >> 6, ml = lane & 15, q = lane >> 4;
    const int swzb = (ml & 7) << 4;
    const char* wbytes = (const char*)wlds;

    // ---- per-wave segment bounds: lanes 0..CPW search in parallel ----
    int lp = lane < CPW ? lane : CPW;
    int probe = c0 + w * CPW + lp; if (probe > S) probe = S;
    const int sr = lower_bound(index, N, probe);
    const int start = __shfl(sr, 0), end = __shfl(sr, CPW);
    const int cw0 = min(c0 + w * CPW, S);
    const int cw1 = min(cw0 + CPW, S);

    // ---- stage weights (swizzled source -> linear LDS); 3 panels x 32 KiB --
#pragma unroll
    for (int i = 0; i < 3; i++) {
        const int cb = (t + i * THREADS) << 5;   // 32 B per thread-chunk, [0, 98304)
        const int r = cb >> 15;
        const int local = cb & 32767;
        const int row = local >> 8;
        const int slot = (local >> 4) & 15;
        const int col8a = ((slot ^ (row & 7)) << 3);
        const int col8b = (((slot + 1) ^ (row & 7)) << 3);
        const float* srcf;
        if (r == 0)      srcf = Wa1 + (size_t)h * 32768 + (size_t)row * 256;
        else if (r == 1) srcf = Wm1 + (size_t)h * 16384 + (size_t)row * 128;
        else             srcf = Wm2 + (size_t)h * 16384 + (size_t)row * 128;
        *(bf16x8*)((char*)wlds + cb)      = cvt8(srcf + col8a);
        *(bf16x8*)((char*)wlds + cb + 16) = cvt8(srcf + col8b);
    }
    if (t < 32) *(float4*)&bm1lds[t * 4] = *(const float4*)&bm1[h * 128 + t * 4];
    __syncthreads();

    // ---- hoisted per-lane biases (col = ot*16+ml of head h) ----
    float ba1v[8], bb2[8], wa2v[8];
#pragma unroll
    for (int ot = 0; ot < 8; ot++) {
        ba1v[ot] = ba1[h * 128 + ot * 16 + ml];
        bb2[ot]  = bm2[h * 128 + ot * 16 + ml];
        wa2v[ot] = Wa2[h * 128 + ot * 16 + ml];
    }
    const float ba2v = ba2[h];

    // ---- precompute cry contribution: D[crystal r][o] = cry_c . Wa1cry^T ----
    // (Wa1 cry-half fragments read from global f32; once per wave)
    {
        bf16x8 cf[4];
#pragma unroll
        for (int kk = 0; kk < 4; kk++) {
            bf16x8 z;
#pragma unroll
            for (int j = 0; j < 8; j++) z[j] = (__bf16)0.f;
            if (ml < CPW && cw0 + ml < S)
                z = cvt8(cry + (size_t)(cw0 + ml) * 128 + kk * 32 + q * 8);
            cf[kk] = z;
        }
#pragma unroll
        for (int ot = 0; ot < 8; ot++) {
            f32x4 acc = {0.f, 0.f, 0.f, 0.f};
#pragma unroll
            for (int kk = 0; kk < 4; kk++) {
                bf16x8 B = cvt8(Wa1 + (size_t)h * 32768 + (size_t)(ot * 16 + ml) * 256
                                + 128 + kk * 32 + q * 8);
                acc = MFMA(cf[kk], B, acc);
            }
            if (q == 0) {
#pragma unroll
                for (int r = 0; r < 4; r++) crylds[w][r][ot * 16 + ml] = acc[r];
            }
        }
    }

    float m_run = -1e30f, d_run = 0.f;
    float wacc[8] = {0.f,0.f,0.f,0.f,0.f,0.f,0.f,0.f};
    int cur_c = -1, emit_c = cw0;

    auto flushf = [&]() {
        float inv = 1.f / (d_run + 1e-16f);
        for (int z = emit_c; z < cur_c; z++)   // zero-fill empty crystals
            *(float2*)&out[(size_t)z * 512 + h * 128 + lane * 2] = make_float2(0.f, 0.f);
#pragma unroll
        for (int ot = 0; ot < 8; ot++) {
            float v = wacc[ot];
            v += __shfl_xor(v, 16);
            v += __shfl_xor(v, 32);
            if (q == 0) out[(size_t)cur_c * 512 + h * 128 + ot * 16 + ml] = v * inv;
            wacc[ot] = 0.f;
        }
        emit_c = cur_c + 1;
        m_run = -1e30f; d_run = 0.f;
    };

    for (int tb = start; tb < end; tb += MT) {
        int nv = end - tb; if (nv > MT) nv = MT;

        // ---- per-lane node index (rows 0..31 on lanes 0..31) ----
        const int iv = (lane < nv) ? index[tb + lane] : cw0;

        // ---- run-boundary mask for the whole tile ----
        unsigned long long bmask;
        {
            int ivp = __shfl(iv, lane > 0 ? lane - 1 : 0);
            bmask = __ballot(lane < nv && (lane == 0 || iv != ivp));
        }

        // ---- two 16-row halves, fully processed in sequence ----
        for (int s = 0; s < 2; s++) {
            const int lo = s * 16;
            if (lo >= nv) break;
            int hcnt = nv - lo; if (hcnt > 16) hcnt = 16;

            // -- fea fragments for this half (f32 -> bf16, zero-pad) --
            bf16x8 afh[4];
            {
                const int row = lo + ml;
                const bool val = row < nv;
#pragma unroll
                for (int kk = 0; kk < 4; kk++) {
                    bf16x8 z;
#pragma unroll
                    for (int j = 0; j < 8; j++) z[j] = (__bf16)0.f;
                    if (val) z = cvt8(fea + (size_t)(tb + row) * 128 + kk * 32 + q * 8);
                    afh[kk] = z;
                }
            }

            // -- GEMM3 (node half of Wa1 from LDS; cry half acc-init) --
            float lv4[4];
            {
                int cl4[4];
#pragma unroll
                for (int r = 0; r < 4; r++)
                    cl4[r] = __shfl(iv, lo + q * 4 + r) - cw0;
                float lsum[4] = {0.f, 0.f, 0.f, 0.f};
#pragma unroll
                for (int ot = 0; ot < 8; ot++) {
                    bf16x8 B[4];
#pragma unroll
                    for (int kk = 0; kk < 4; kk++)
                        B[kk] = *(const bf16x8*)(wbytes + LA1B + (ot * 16 + ml) * 256 + ((((kk * 4 + q) << 4)) ^ swzb));
                    const int oc = ot * 16 + ml;
                    f32x4 acc;
#pragma unroll
                    for (int r = 0; r < 4; r++) acc[r] = crylds[w][cl4[r]][oc];
#pragma unroll
                    for (int kk = 0; kk < 4; kk++) acc = MFMA(afh[kk], B[kk], acc);
#pragma unroll
                    for (int r = 0; r < 4; r++) {
                        float v = acc[r] + ba1v[ot]; v = v >= 0.f ? v : 0.01f * v;
                        lsum[r] += v * wa2v[ot];
                    }
                }
#pragma unroll
                for (int rr = 0; rr < 4; rr++) {
                    float x = lsum[rr];
                    x += __shfl_xor(x, 1); x += __shfl_xor(x, 2);
                    x += __shfl_xor(x, 4); x += __shfl_xor(x, 8);
                    lv4[rr] = x + ba2v;   // logit of row lo + q*4 + rr
                }
            }

            // -- GEMM1 swapped (A=Wm1 from LDS, B=fea half) + repack --
            bf16x8 a2h[4];
#pragma unroll
            for (int kk = 0; kk < 4; kk++) {
                unsigned pw[2][2];   // [otl][p]
#pragma unroll
                for (int otl = 0; otl < 2; otl++) {
                    const int ot = kk * 2 + otl;
                    bf16x8 A[4];
#pragma unroll
                    for (int k4 = 0; k4 < 4; k4++)
                        A[k4] = *(const bf16x8*)(wbytes + LM1B + (ot * 16 + ml) * 256 + ((((k4 * 4 + q) << 4)) ^ swzb));
                    const float4 bq = *(const float4*)&bm1lds[ot * 16 + q * 4];
                    f32x4 acc = {0.f, 0.f, 0.f, 0.f};
#pragma unroll
                    for (int k4 = 0; k4 < 4; k4++) acc = MFMA(A[k4], afh[k4], acc);
                    float v0 = acc[0] + bq.x, v1 = acc[1] + bq.y;
                    float v2 = acc[2] + bq.z, v3 = acc[3] + bq.w;
                    v0 = v0 >= 0.f ? v0 : 0.01f * v0;  v1 = v1 >= 0.f ? v1 : 0.01f * v1;
                    v2 = v2 >= 0.f ? v2 : 0.01f * v2;  v3 = v3 >= 0.f ? v3 : 0.01f * v3;
                    pw[otl][0] = pk2(v0, v1);
                    pw[otl][1] = pk2(v2, v3);
                }
                const int srcLo = (((2 * q) & 3) << 4) + ml;
                const int srcHi = (((2 * q + 1) & 3) << 4) + ml;
                const bool hiSel = (q >> 1) & 1;
                unsigned l0a = (unsigned)__shfl((int)pw[0][0], srcLo);
                unsigned l0b = (unsigned)__shfl((int)pw[1][0], srcLo);
                unsigned l1a = (unsigned)__shfl((int)pw[0][1], srcLo);
                unsigned l1b = (unsigned)__shfl((int)pw[1][1], srcLo);
                unsigned h0a = (unsigned)__shfl((int)pw[0][0], srcHi);
                unsigned h0b = (unsigned)__shfl((int)pw[1][0], srcHi);
                unsigned h1a = (unsigned)__shfl((int)pw[0][1], srcHi);
                unsigned h1b = (unsigned)__shfl((int)pw[1][1], srcHi);
                u32x4 wv4u = { hiSel ? l0b : l0a, hiSel ? l1b : l1a,
                               hiSel ? h0b : h0a, hiSel ? h1b : h1a };
                a2h[kk] = __builtin_bit_cast(bf16x8, wv4u);
            }

            // -- GEMM2 (Wm2 from LDS; bias-initialized accumulators) --
            f32x4 acc2h[8];
#pragma unroll
            for (int ot = 0; ot < 8; ot++) {
                bf16x8 B[4];
#pragma unroll
                for (int kk = 0; kk < 4; kk++)
                    B[kk] = *(const bf16x8*)(wbytes + LM2B + (ot * 16 + ml) * 256 + ((((kk * 4 + q) << 4)) ^ swzb));
                f32x4 acc = {bb2[ot], bb2[ot], bb2[ot], bb2[ot]};
#pragma unroll
                for (int kk = 0; kk < 4; kk++) acc = MFMA(a2h[kk], B[kk], acc);
                acc2h[ot] = acc;
            }

            // -- run walk for this half's rows [lo, lo+hcnt) --
            unsigned hm = (unsigned)((bmask >> lo) & 0xffffull) | 1u;
            if (hcnt < 16) hm &= (1u << hcnt) - 1u;
            while (hm) {
                int a = (int)__builtin_ctz(hm);
                hm &= hm - 1u;
                int b = hm ? (int)__builtin_ctz(hm) : hcnt;
                int c = __shfl(iv, lo + a);
                if (c != cur_c) {
                    if (cur_c >= 0) flushf();
                    cur_c = c;
                }
                float tmax = -1e30f;
#pragma unroll
                for (int rr = 0; rr < 4; rr++) {
                    int row = q * 4 + rr;
                    if (row >= a && row < b) tmax = fmaxf(tmax, lv4[rr]);
                }
                tmax = fmaxf(tmax, __shfl_xor(tmax, 16));
                tmax = fmaxf(tmax, __shfl_xor(tmax, 32));
                float m_new = fmaxf(m_run, tmax);
                float scf = __expf(m_run - m_new);
                d_run *= scf;
#pragma unroll
                for (int ot = 0; ot < 8; ot++) wacc[ot] *= scf;
                m_run = m_new;

                float wv4[4]; float dp = 0.f;
#pragma unroll
                for (int rr = 0; rr < 4; rr++) {
                    int row = q * 4 + rr;
                    float ww = (row >= a && row < b) ? __expf(lv4[rr] - m_run) : 0.f;
                    wv4[rr] = ww; dp += ww;
                }
                dp += __shfl_xor(dp, 16);
                dp += __shfl_xor(dp, 32);
                d_run += dp;
#pragma unroll
                for (int ot = 0; ot < 8; ot++) {
                    f32x4 acc = acc2h[ot];
                    wacc[ot] += wv4[0] * acc[0] + wv4[1] * acc[1]
                              + wv4[2] * acc[2] + wv4[3] * acc[3];
                }
            }
        }
    }

    if (cur_c >= 0) flushf();
    for (int z = emit_c; z < cw1; z++)   // trailing empty crystals
        *(float2*)&out[(size_t)z * 512 + h * 128 + lane * 2] = make_float2(0.f, 0.f);
}

// ---------------------------------------------------------------------------
extern "C" void kernel_launch(void* const* d_in, const int* in_sizes, int n_in,
                              void* d_out, int out_size, void* d_ws, size_t ws_size,
                              hipStream_t stream)
{
    const float* fea = (const float*)d_in[0];
    const float* cry = (const float*)d_in[1];
    const float* Wm1 = (const float*)d_in[2];
    const float* bm1 = (const float*)d_in[3];
    const float* Wm2 = (const float*)d_in[4];
    const float* bm2 = (const float*)d_in[5];
    const float* Wa1 = (const float*)d_in[6];
    const float* ba1 = (const float*)d_in[7];
    const float* Wa2 = (const float*)d_in[8];
    const float* ba2 = (const float*)d_in[9];
    const int* index = (const int*)d_in[10];

    const int N = in_sizes[0] / 128;      // 200000
    const int S = out_size / 512;         // 16384
    const int G = (S + CPB - 1) / CPB;
    const int grid = 4 * G;

    fused8_kernel<<<grid, THREADS, 0, stream>>>(
        fea, cry, Wm1, bm1, Wm2, bm2, Wa1, ba1, Wa2, ba2,
        index, N, S, (float*)d_out);
}

// Round 8
// 502.126 us; speedup vs baseline: 1.1490x; 1.1370x over previous
//
#include <hip/hip_runtime.h>

typedef __bf16 bf16x8 __attribute__((ext_vector_type(8)));
typedef float  f32x4  __attribute__((ext_vector_type(4)));
typedef unsigned int u32x4 __attribute__((ext_vector_type(4)));

#define MFMA(a, b, c) __builtin_amdgcn_mfma_f32_16x16x32_bf16((a), (b), (c), 0, 0, 0)

#define MT 32    // nodes per tile (2 x 16-row halves)

// workspace layout: [seg table][bf16 weight pack][bf16 cry][bf16 fea]
#define SEG_INTS  16416
#define SEG_BYTES (SEG_INTS * 4)       // 65664
#define O_WM1 0
#define O_WM2 65536
#define O_WA1 131072
#define O_WA2 262144
#define W_ELEMS 262656
#define W_BYTES (W_ELEMS * 2)          // 525312

__device__ __forceinline__ bf16x8 cvt8(const float* pf) {
    float4 a = *(const float4*)pf, b = *(const float4*)(pf + 4);
    bf16x8 o;
    o[0] = (__bf16)a.x; o[1] = (__bf16)a.y; o[2] = (__bf16)a.z; o[3] = (__bf16)a.w;
    o[4] = (__bf16)b.x; o[5] = (__bf16)b.y; o[6] = (__bf16)b.z; o[7] = (__bf16)b.w;
    return o;
}

__device__ __forceinline__ unsigned pk2(float a, float b) {
    unsigned short ua = __builtin_bit_cast(unsigned short, (__bf16)a);
    unsigned short ub = __builtin_bit_cast(unsigned short, (__bf16)b);
    return (unsigned)ua | ((unsigned)ub << 16);
}

__device__ __forceinline__ int lower_bound(const int* __restrict__ a, int n, int v) {
    int lo = 0, hi = n;
    while (lo < hi) { int mid = (lo + hi) >> 1; if (a[mid] < v) lo = mid + 1; else hi = mid; }
    return lo;
}

template<bool WB>
__device__ __forceinline__ bf16x8 wfrag(const __bf16* wb, const float* wf, size_t idx) {
    if constexpr (WB) return *(const bf16x8*)(wb + idx);
    else              return cvt8(wf + idx);
}

// ---------------------------------------------------------------------------
// Merged prep: block ranges do [seg table][weight pack][cry cast][fea cast].
// bf16 casts are bitwise-identical to the in-kernel cvt8 rounding.
// ---------------------------------------------------------------------------
__global__ __launch_bounds__(256) void prep3_kernel(
    const float* __restrict__ Wm1, const float* __restrict__ Wm2,
    const float* __restrict__ Wa1, const float* __restrict__ Wa2,
    const float* __restrict__ fea, const float* __restrict__ cry,
    const int* __restrict__ index, int N, int S,
    int segBlocks, int packBlocks, int cryBlocks,
    int* __restrict__ seg, __bf16* __restrict__ wb,
    __bf16* __restrict__ cryb, __bf16* __restrict__ feab, int full)
{
    int b = blockIdx.x;
    if (b < segBlocks) {
        int c = b * 256 + threadIdx.x;
        if (c <= S) seg[c] = lower_bound(index, N, c);
        return;
    }
    if (!full) return;
    b -= segBlocks;
    if (b < packBlocks) {
        int i8 = b * 256 + threadIdx.x;
        if (i8 >= W_ELEMS / 8) return;
        int i = i8 * 8;
        const float* src; int s;
        if      (i < O_WM2) { src = Wm1; s = i; }
        else if (i < O_WA1) { src = Wm2; s = i - O_WM2; }
        else if (i < O_WA2) { src = Wa1; s = i - O_WA1; }
        else                { src = Wa2; s = i - O_WA2; }
        *(bf16x8*)(wb + i) = cvt8(src + s);
        return;
    }
    b -= packBlocks;
    if (b < cryBlocks) {
        int i = b * 256 + threadIdx.x;
        if (i < S * 16) *(bf16x8*)(cryb + (size_t)i * 8) = cvt8(cry + (size_t)i * 8);
        return;
    }
    b -= cryBlocks;
    int i = b * 256 + threadIdx.x;
    if (i < N * 16) *(bf16x8*)(feab + (size_t)i * 8) = cvt8(fea + (size_t)i * 8);
}

// ---------------------------------------------------------------------------
// Shared fused body. TPB threads (TPB/64 waves), one head x (WAVES*CPWT)
// crystals per block; wave w owns CPWT crystals; no main-loop barriers.
// LDSA1=true: all three panels (Wa1 node half, Wm1, Wm2) in LDS (96 KiB).
// LDSA1=false: Wm1+Wm2 in LDS (64 KiB); Wa1 node half read from the
// L2-resident bf16 pack inside GEMM3. XOR-swizzled panels; XCD-aware block
// mapping keeps a crystal-group's 4 heads on one XCD. Per 32-node tile:
// two 16-row halves, each fully processed (GEMM3->logits, GEMM1 swapped +
// in-reg repack, GEMM2, softmax run-walk) to bound live registers.
// MFMA 16x16x32 bf16: A/B[idx=lane&15][k=(lane>>4)*8+j]; D col=lane&15,
// row=(lane>>4)*4+reg.
// ---------------------------------------------------------------------------
template<int TPB, int CPWT, bool LDSA1, bool WB, bool SEG, bool FB>
__device__ __forceinline__ void fused_body(
    const float* __restrict__ fea, const float* __restrict__ cry,
    const float* __restrict__ Wm1, const float* __restrict__ bm1,
    const float* __restrict__ Wm2, const float* __restrict__ bm2,
    const float* __restrict__ Wa1, const float* __restrict__ ba1,
    const float* __restrict__ Wa2, const float* __restrict__ ba2,
    const __bf16* __restrict__ wb, const int* __restrict__ seg,
    const __bf16* __restrict__ feab, const __bf16* __restrict__ cryb,
    const int* __restrict__ index, int N, int S, float* __restrict__ out)
{
    constexpr int NW   = TPB / 64;
    constexpr int CPBt = NW * CPWT;
    constexpr int PANELS = LDSA1 ? 3 : 2;
    constexpr int PBYTES = PANELS * 32768;
    constexpr int LM1B_ = LDSA1 ? 32768 : 0;
    constexpr int LM2B_ = LDSA1 ? 65536 : 32768;

    __shared__ __align__(16) __bf16 wlds[PBYTES / 2];
    __shared__ float crylds[NW][CPWT][128];

    // ---- XCD-aware block -> (head, crystal-group) mapping ----
    const int G = (S + CPBt - 1) / CPBt;
    int h, cg;
    if ((G & 7) == 0) {
        const int xcd = blockIdx.x & 7, j = blockIdx.x >> 3;
        h = j & 3; cg = xcd + 8 * (j >> 2);
    } else {
        h = blockIdx.x & 3; cg = blockIdx.x >> 2;
    }
    const int c0 = cg * CPBt;
    const int t  = threadIdx.x;
    const int lane = t & 63, w = t >> 6, ml = lane & 15, q = lane >> 4;
    const int swzb = (ml & 7) << 4;
    const char* wbytes = (const char*)wlds;

    // ---- stage weight panels (swizzled source -> linear LDS) ----
    constexpr int NSTG = PBYTES / (TPB * 16);
#pragma unroll
    for (int i = 0; i < NSTG; i++) {
        const int cb = (t + i * TPB) << 4;
        const int r = cb >> 15;
        const int local = cb & 32767;
        const int row = local >> 8;
        const int col8 = ((((local >> 4) & 15) ^ (row & 7)) << 3);
        bf16x8 v;
        if constexpr (LDSA1) {
            if (r == 0)      v = wfrag<WB>(wb + O_WA1, Wa1, (size_t)h * 32768 + (size_t)row * 256 + col8);
            else if (r == 1) v = wfrag<WB>(wb + O_WM1, Wm1, (size_t)h * 16384 + (size_t)row * 128 + col8);
            else             v = wfrag<WB>(wb + O_WM2, Wm2, (size_t)h * 16384 + (size_t)row * 128 + col8);
        } else {
            if (r == 0)      v = wfrag<WB>(wb + O_WM1, Wm1, (size_t)h * 16384 + (size_t)row * 128 + col8);
            else             v = wfrag<WB>(wb + O_WM2, Wm2, (size_t)h * 16384 + (size_t)row * 128 + col8);
        }
        *(bf16x8*)((char*)wlds + cb) = v;
    }
    __syncthreads();

    // ---- per-wave crystal range ----
    const int cw0 = min(c0 + w * CPWT, S);
    const int cw1 = min(cw0 + CPWT, S);
    int start, end;
    if constexpr (SEG) { start = seg[cw0]; end = seg[cw1]; }
    else {
        int lp = lane < CPWT ? lane : CPWT;
        int probe = c0 + w * CPWT + lp; if (probe > S) probe = S;
        const int sr = lower_bound(index, N, probe);
        start = __shfl(sr, 0); end = __shfl(sr, CPWT);
    }

    // ---- hoisted per-lane biases (col = ot*16+ml of head h) ----
    float ba1v[8], bb2[8], wa2v[8];
#pragma unroll
    for (int ot = 0; ot < 8; ot++) {
        ba1v[ot] = ba1[h * 128 + ot * 16 + ml];
        bb2[ot]  = bm2[h * 128 + ot * 16 + ml];
        wa2v[ot] = Wa2[h * 128 + ot * 16 + ml];
    }
    const float ba2v = ba2[h];
    const float* bm1h = bm1 + h * 128;

    // ---- precompute cry contribution: D[crystal r][o] = cry_c . Wa1cry^T ----
    {
        bf16x8 cf[4];
#pragma unroll
        for (int kk = 0; kk < 4; kk++) {
            bf16x8 z;
#pragma unroll
            for (int j = 0; j < 8; j++) z[j] = (__bf16)0.f;
            if (ml < CPWT && cw0 + ml < S) {
                if constexpr (FB) z = *(const bf16x8*)(cryb + (size_t)(cw0 + ml) * 128 + kk * 32 + q * 8);
                else              z = cvt8(cry + (size_t)(cw0 + ml) * 128 + kk * 32 + q * 8);
            }
            cf[kk] = z;
        }
#pragma unroll
        for (int ot = 0; ot < 8; ot++) {
            size_t wrow = (size_t)h * 32768 + (size_t)(ot * 16 + ml) * 256;
            f32x4 acc = {0.f, 0.f, 0.f, 0.f};
#pragma unroll
            for (int kk = 0; kk < 4; kk++)
                acc = MFMA(cf[kk], wfrag<WB>(wb + O_WA1, Wa1, wrow + 128 + kk * 32 + q * 8), acc);
            if (q == 0) {
#pragma unroll
                for (int r = 0; r < 4; r++)
                    if (r < CPWT) crylds[w][r < CPWT ? r : 0][ot * 16 + ml] = acc[r];
            }
        }
    }

    float m_run = -1e30f, d_run = 0.f;
    float wacc[8] = {0.f,0.f,0.f,0.f,0.f,0.f,0.f,0.f};
    int cur_c = -1, emit_c = cw0;

    auto flushf = [&]() {
        float inv = 1.f / (d_run + 1e-16f);
        for (int z = emit_c; z < cur_c; z++)   // zero-fill empty crystals
            *(float2*)&out[(size_t)z * 512 + h * 128 + lane * 2] = make_float2(0.f, 0.f);
#pragma unroll
        for (int ot = 0; ot < 8; ot++) {
            float v = wacc[ot];
            v += __shfl_xor(v, 16);
            v += __shfl_xor(v, 32);
            if (q == 0) out[(size_t)cur_c * 512 + h * 128 + ot * 16 + ml] = v * inv;
            wacc[ot] = 0.f;
        }
        emit_c = cur_c + 1;
        m_run = -1e30f; d_run = 0.f;
    };

    for (int tb = start; tb < end; tb += MT) {
        int nv = end - tb; if (nv > MT) nv = MT;

        // ---- per-lane node index (rows 0..31 on lanes 0..31) ----
        const int iv = (lane < nv) ? index[tb + lane] : cw0;

        // ---- run-boundary mask for the whole tile ----
        unsigned long long bmask;
        {
            int ivp = __shfl(iv, lane > 0 ? lane - 1 : 0);
            bmask = __ballot(lane < nv && (lane == 0 || iv != ivp));
        }

        // ---- two 16-row halves, fully processed in sequence ----
        for (int s = 0; s < 2; s++) {
            const int lo = s * 16;
            if (lo >= nv) break;
            int hcnt = nv - lo; if (hcnt > 16) hcnt = 16;

            // -- fea fragments for this half (zero-pad invalid rows) --
            bf16x8 afh[4];
            {
                const int row = lo + ml;
                const bool val = row < nv;
#pragma unroll
                for (int kk = 0; kk < 4; kk++) {
                    bf16x8 z;
#pragma unroll
                    for (int j = 0; j < 8; j++) z[j] = (__bf16)0.f;
                    if (val) {
                        if constexpr (FB) z = *(const bf16x8*)(feab + (size_t)(tb + row) * 128 + kk * 32 + q * 8);
                        else              z = cvt8(fea + (size_t)(tb + row) * 128 + kk * 32 + q * 8);
                    }
                    afh[kk] = z;
                }
            }

            // -- GEMM3 (Wa1 node half; cry half as acc-init) -> logits --
            float lv4[4];
            {
                int cl4[4];
#pragma unroll
                for (int r = 0; r < 4; r++)
                    cl4[r] = __shfl(iv, lo + q * 4 + r) - cw0;
                float lsum[4] = {0.f, 0.f, 0.f, 0.f};
#pragma unroll
                for (int ot = 0; ot < 8; ot++) {
                    const int oc = ot * 16 + ml;
                    f32x4 acc;
#pragma unroll
                    for (int r = 0; r < 4; r++) acc[r] = crylds[w][cl4[r]][oc];
                    if constexpr (LDSA1) {
                        bf16x8 B[4];
#pragma unroll
                        for (int kk = 0; kk < 4; kk++)
                            B[kk] = *(const bf16x8*)(wbytes + (ot * 16 + ml) * 256 + ((((kk * 4 + q) << 4)) ^ swzb));
#pragma unroll
                        for (int kk = 0; kk < 4; kk++) acc = MFMA(afh[kk], B[kk], acc);
                    } else {
                        size_t wrow = (size_t)h * 32768 + (size_t)(ot * 16 + ml) * 256;
#pragma unroll
                        for (int kk = 0; kk < 4; kk++)
                            acc = MFMA(afh[kk], wfrag<WB>(wb + O_WA1, Wa1, wrow + kk * 32 + q * 8), acc);
                    }
#pragma unroll
                    for (int r = 0; r < 4; r++) {
                        float v = acc[r] + ba1v[ot]; v = v >= 0.f ? v : 0.01f * v;
                        lsum[r] += v * wa2v[ot];
                    }
                }
#pragma unroll
                for (int rr = 0; rr < 4; rr++) {
                    float x = lsum[rr];
                    x += __shfl_xor(x, 1); x += __shfl_xor(x, 2);
                    x += __shfl_xor(x, 4); x += __shfl_xor(x, 8);
                    lv4[rr] = x + ba2v;   // logit of row lo + q*4 + rr
                }
            }

            // -- GEMM1 swapped (A=Wm1 from LDS, B=fea half) + repack --
            bf16x8 a2h[4];
#pragma unroll
            for (int kk = 0; kk < 4; kk++) {
                unsigned pw[2][2];   // [otl][p]
#pragma unroll
                for (int otl = 0; otl < 2; otl++) {
                    const int ot = kk * 2 + otl;
                    bf16x8 A[4];
#pragma unroll
                    for (int k4 = 0; k4 < 4; k4++)
                        A[k4] = *(const bf16x8*)(wbytes + LM1B_ + (ot * 16 + ml) * 256 + ((((k4 * 4 + q) << 4)) ^ swzb));
                    const float4 bq = *(const float4*)&bm1h[ot * 16 + q * 4];
                    f32x4 acc = {0.f, 0.f, 0.f, 0.f};
#pragma unroll
                    for (int k4 = 0; k4 < 4; k4++) acc = MFMA(A[k4], afh[k4], acc);
                    float v0 = acc[0] + bq.x, v1 = acc[1] + bq.y;
                    float v2 = acc[2] + bq.z, v3 = acc[3] + bq.w;
                    v0 = v0 >= 0.f ? v0 : 0.01f * v0;  v1 = v1 >= 0.f ? v1 : 0.01f * v1;
                    v2 = v2 >= 0.f ? v2 : 0.01f * v2;  v3 = v3 >= 0.f ? v3 : 0.01f * v3;
                    pw[otl][0] = pk2(v0, v1);
                    pw[otl][1] = pk2(v2, v3);
                }
                const int srcLo = (((2 * q) & 3) << 4) + ml;
                const int srcHi = (((2 * q + 1) & 3) << 4) + ml;
                const bool hiSel = (q >> 1) & 1;
                unsigned l0a = (unsigned)__shfl((int)pw[0][0], srcLo);
                unsigned l0b = (unsigned)__shfl((int)pw[1][0], srcLo);
                unsigned l1a = (unsigned)__shfl((int)pw[0][1], srcLo);
                unsigned l1b = (unsigned)__shfl((int)pw[1][1], srcLo);
                unsigned h0a = (unsigned)__shfl((int)pw[0][0], srcHi);
                unsigned h0b = (unsigned)__shfl((int)pw[1][0], srcHi);
                unsigned h1a = (unsigned)__shfl((int)pw[0][1], srcHi);
                unsigned h1b = (unsigned)__shfl((int)pw[1][1], srcHi);
                u32x4 wv4u = { hiSel ? l0b : l0a, hiSel ? l1b : l1a,
                               hiSel ? h0b : h0a, hiSel ? h1b : h1a };
                a2h[kk] = __builtin_bit_cast(bf16x8, wv4u);
            }

            // -- GEMM2 (Wm2 from LDS; bias-initialized accumulators) --
            f32x4 acc2h[8];
#pragma unroll
            for (int ot = 0; ot < 8; ot++) {
                bf16x8 B[4];
#pragma unroll
                for (int kk = 0; kk < 4; kk++)
                    B[kk] = *(const bf16x8*)(wbytes + LM2B_ + (ot * 16 + ml) * 256 + ((((kk * 4 + q) << 4)) ^ swzb));
                f32x4 acc = {bb2[ot], bb2[ot], bb2[ot], bb2[ot]};
#pragma unroll
                for (int kk = 0; kk < 4; kk++) acc = MFMA(a2h[kk], B[kk], acc);
                acc2h[ot] = acc;
            }

            // -- run walk for this half's rows [lo, lo+hcnt) --
            unsigned hm = (unsigned)((bmask >> lo) & 0xffffull) | 1u;
            if (hcnt < 16) hm &= (1u << hcnt) - 1u;
            while (hm) {
                int a = (int)__builtin_ctz(hm);
                hm &= hm - 1u;
                int b = hm ? (int)__builtin_ctz(hm) : hcnt;
                int c = __shfl(iv, lo + a);
                if (c != cur_c) {
                    if (cur_c >= 0) flushf();
                    cur_c = c;
                }
                float tmax = -1e30f;
#pragma unroll
                for (int rr = 0; rr < 4; rr++) {
                    int row = q * 4 + rr;
                    if (row >= a && row < b) tmax = fmaxf(tmax, lv4[rr]);
                }
                tmax = fmaxf(tmax, __shfl_xor(tmax, 16));
                tmax = fmaxf(tmax, __shfl_xor(tmax, 32));
                float m_new = fmaxf(m_run, tmax);
                float scf = __expf(m_run - m_new);
                d_run *= scf;
#pragma unroll
                for (int ot = 0; ot < 8; ot++) wacc[ot] *= scf;
                m_run = m_new;

                float wv4[4]; float dp = 0.f;
#pragma unroll
                for (int rr = 0; rr < 4; rr++) {
                    int row = q * 4 + rr;
                    float ww = (row >= a && row < b) ? __expf(lv4[rr] - m_run) : 0.f;
                    wv4[rr] = ww; dp += ww;
                }
                dp += __shfl_xor(dp, 16);
                dp += __shfl_xor(dp, 32);
                d_run += dp;
#pragma unroll
                for (int ot = 0; ot < 8; ot++) {
                    f32x4 acc = acc2h[ot];
                    wacc[ot] += wv4[0] * acc[0] + wv4[1] * acc[1]
                              + wv4[2] * acc[2] + wv4[3] * acc[3];
                }
            }
        }
    }

    if (cur_c >= 0) flushf();
    for (int z = emit_c; z < cw1; z++)   // trailing empty crystals
        *(float2*)&out[(size_t)z * 512 + h * 128 + lane * 2] = make_float2(0.f, 0.f);
}

// ---- Variant A: 1024 thr, 4 waves/EU pinned (VGPR budget 128), all-LDS ----
__global__ __attribute__((amdgpu_flat_work_group_size(1024, 1024),
                          amdgpu_waves_per_eu(4, 4)))
void fusedA_kernel(
    const float* __restrict__ fea, const float* __restrict__ cry,
    const float* __restrict__ Wm1, const float* __restrict__ bm1,
    const float* __restrict__ Wm2, const float* __restrict__ bm2,
    const float* __restrict__ Wa1, const float* __restrict__ ba1,
    const float* __restrict__ Wa2, const float* __restrict__ ba2,
    const __bf16* __restrict__ wb, const int* __restrict__ seg,
    const __bf16* __restrict__ feab, const __bf16* __restrict__ cryb,
    const int* __restrict__ index, int N, int S, float* __restrict__ out)
{
    fused_body<1024, 4, true, true, true, true>(fea, cry, Wm1, bm1, Wm2, bm2,
        Wa1, ba1, Wa2, ba2, wb, seg, feab, cryb, index, N, S, out);
}

// ---- Variant B: 512 thr, (512,2) proven regalloc, 72 KiB LDS, Wa1 via L2 --
__global__ __launch_bounds__(512, 2)
void fusedB_full(
    const float* __restrict__ fea, const float* __restrict__ cry,
    const float* __restrict__ Wm1, const float* __restrict__ bm1,
    const float* __restrict__ Wm2, const float* __restrict__ bm2,
    const float* __restrict__ Wa1, const float* __restrict__ ba1,
    const float* __restrict__ Wa2, const float* __restrict__ ba2,
    const __bf16* __restrict__ wb, const int* __restrict__ seg,
    const __bf16* __restrict__ feab, const __bf16* __restrict__ cryb,
    const int* __restrict__ index, int N, int S, float* __restrict__ out)
{
    fused_body<512, 2, false, true, true, true>(fea, cry, Wm1, bm1, Wm2, bm2,
        Wa1, ba1, Wa2, ba2, wb, seg, feab, cryb, index, N, S, out);
}

__global__ __launch_bounds__(512, 2)
void fusedB_seg(
    const float* __restrict__ fea, const float* __restrict__ cry,
    const float* __restrict__ Wm1, const float* __restrict__ bm1,
    const float* __restrict__ Wm2, const float* __restrict__ bm2,
    const float* __restrict__ Wa1, const float* __restrict__ ba1,
    const float* __restrict__ Wa2, const float* __restrict__ ba2,
    const __bf16* __restrict__ wb, const int* __restrict__ seg,
    const __bf16* __restrict__ feab, const __bf16* __restrict__ cryb,
    const int* __restrict__ index, int N, int S, float* __restrict__ out)
{
    fused_body<512, 2, false, false, true, false>(fea, cry, Wm1, bm1, Wm2, bm2,
        Wa1, ba1, Wa2, ba2, wb, seg, feab, cryb, index, N, S, out);
}

__global__ __launch_bounds__(512, 2)
void fusedB_none(
    const float* __restrict__ fea, const float* __restrict__ cry,
    const float* __restrict__ Wm1, const float* __restrict__ bm1,
    const float* __restrict__ Wm2, const float* __restrict__ bm2,
    const float* __restrict__ Wa1, const float* __restrict__ ba1,
    const float* __restrict__ Wa2, const float* __restrict__ ba2,
    const __bf16* __restrict__ wb, const int* __restrict__ seg,
    const __bf16* __restrict__ feab, const __bf16* __restrict__ cryb,
    const int* __restrict__ index, int N, int S, float* __restrict__ out)
{
    fused_body<512, 2, false, false, false, false>(fea, cry, Wm1, bm1, Wm2, bm2,
        Wa1, ba1, Wa2, ba2, wb, seg, feab, cryb, index, N, S, out);
}

// ---------------------------------------------------------------------------
extern "C" void kernel_launch(void* const* d_in, const int* in_sizes, int n_in,
                              void* d_out, int out_size, void* d_ws, size_t ws_size,
                              hipStream_t stream)
{
    const float* fea = (const float*)d_in[0];
    const float* cry = (const float*)d_in[1];
    const float* Wm1 = (const float*)d_in[2];
    const float* bm1 = (const float*)d_in[3];
    const float* Wm2 = (const float*)d_in[4];
    const float* bm2 = (const float*)d_in[5];
    const float* Wa1 = (const float*)d_in[6];
    const float* ba1 = (const float*)d_in[7];
    const float* Wa2 = (const float*)d_in[8];
    const float* ba2 = (const float*)d_in[9];
    const int* index = (const int*)d_in[10];

    const int N = in_sizes[0] / 128;      // 200000
    const int S = out_size / 512;         // 16384

    // runtime regalloc check: was the 128-VGPR budget honored for variant A?
    static int useA = -1;
    if (useA < 0) {
        hipFuncAttributes fa{};
        hipError_t e = hipFuncGetAttributes(&fa, reinterpret_cast<const void*>(fusedA_kernel));
        useA = (e == hipSuccess && fa.numRegs >= 80) ? 1 : 0;
    }

    const int gridA = 4 * ((S + 63) / 64);    // CPB=64
    const int gridB = 4 * ((S + 15) / 16);    // CPB=16

    const int segBlocks  = (S + 1 + 255) / 256;
    const int packBlocks = (W_ELEMS / 8 + 255) / 256;
    const int cryBlocks  = (S * 16 + 255) / 256;
    const int feaBlocks  = (N * 16 + 255) / 256;
    const bool segFits = (S + 1) <= SEG_INTS;

    const size_t wOff   = (size_t)SEG_BYTES;
    const size_t cryOff = wOff + (size_t)W_BYTES;
    const size_t feaOff = cryOff + (size_t)S * 256;
    const size_t needSeg  = (size_t)SEG_BYTES;
    const size_t needFull = feaOff + (size_t)N * 256;

    if (segFits && ws_size >= needFull) {
        int* seg = (int*)d_ws;
        __bf16* wbp  = (__bf16*)((char*)d_ws + wOff);
        __bf16* cryb = (__bf16*)((char*)d_ws + cryOff);
        __bf16* feab = (__bf16*)((char*)d_ws + feaOff);
        prep3_kernel<<<segBlocks + packBlocks + cryBlocks + feaBlocks, 256, 0, stream>>>(
            Wm1, Wm2, Wa1, Wa2, fea, cry, index, N, S,
            segBlocks, packBlocks, cryBlocks, seg, wbp, cryb, feab, 1);
        if (useA)
            fusedA_kernel<<<gridA, 1024, 0, stream>>>(
                fea, cry, Wm1, bm1, Wm2, bm2, Wa1, ba1, Wa2, ba2,
                wbp, seg, feab, cryb, index, N, S, (float*)d_out);
        else
            fusedB_full<<<gridB, 512, 0, stream>>>(
                fea, cry, Wm1, bm1, Wm2, bm2, Wa1, ba1, Wa2, ba2,
                wbp, seg, feab, cryb, index, N, S, (float*)d_out);
    } else if (segFits && ws_size >= needSeg) {
        int* seg = (int*)d_ws;
        prep3_kernel<<<segBlocks, 256, 0, stream>>>(
            Wm1, Wm2, Wa1, Wa2, fea, cry, index, N, S,
            segBlocks, packBlocks, cryBlocks, seg, nullptr, nullptr, nullptr, 0);
        fusedB_seg<<<gridB, 512, 0, stream>>>(
            fea, cry, Wm1, bm1, Wm2, bm2, Wa1, ba1, Wa2, ba2,
            nullptr, seg, nullptr, nullptr, index, N, S, (float*)d_out);
    } else {
        fusedB_none<<<gridB, 512, 0, stream>>>(
            fea, cry, Wm1, bm1, Wm2, bm2, Wa1, ba1, Wa2, ba2,
            nullptr, nullptr, nullptr, nullptr, index, N, S, (float*)d_out);
    }
}